// Round 9
// baseline (417.456 us; speedup 1.0000x reference)
//
#include <hip/hip_runtime.h>

#define NN 8192
#define TT 60
#define DF 6
#define HH 64
#define GG 256   // 4*H
#define RS 132   // sorted-row stride: [0..63] u*last, [64..127] w*last, [128] u, [129] w
#define CH 32    // rows per chunk = rows per block slice
#define NB 256   // tail grid = #chunks = #blocks

typedef _Float16 half8 __attribute__((ext_vector_type(8)));
typedef float f32x4 __attribute__((ext_vector_type(4)));
#define MFMA16(a, b, c) __builtin_amdgcn_mfma_f32_16x16x32_f16((a), (b), (c), 0, 0, 0)

__device__ __forceinline__ float sigmoidf_(float x) {
    return __builtin_amdgcn_rcpf(1.0f + __expf(-x));
}
__device__ __forceinline__ float tanhf_(float x) {
    return __builtin_fmaf(2.0f, __builtin_amdgcn_rcpf(1.0f + __expf(-2.0f * x)), -1.0f);
}
__device__ __forceinline__ float lrelu_(float x) { return x > 0.0f ? x : 0.01f * x; }

__device__ __forceinline__ half8 ldw8(const float* __restrict__ p) {
    const float4* q = (const float4*)p;
    float4 u = q[0], v = q[1];
    half8 r;
    r[0]=(_Float16)u.x; r[1]=(_Float16)u.y; r[2]=(_Float16)u.z; r[3]=(_Float16)u.w;
    r[4]=(_Float16)v.x; r[5]=(_Float16)v.y; r[6]=(_Float16)v.z; r[7]=(_Float16)v.w;
    return r;
}

// ---------------------------------------------------------------------------
// MFMA 2-layer LSTM, software-pipelined across layers (unchanged from R7).
// ---------------------------------------------------------------------------
#define SXW (TT * 8 + 8)

__global__ __launch_bounds__(512, 4)
void lstm_fused_kernel(const float* __restrict__ x,
                       const float* __restrict__ Wih0, const float* __restrict__ Whh0,
                       const float* __restrict__ bih0, const float* __restrict__ bhh0,
                       const float* __restrict__ Wih1, const float* __restrict__ Whh1,
                       const float* __restrict__ bih1, const float* __restrict__ bhh1,
                       float* __restrict__ last_out)
{
    __shared__ _Float16 sxp[16][SXW];
    __shared__ _Float16 h0buf[2][16][72];
    __shared__ _Float16 h1buf[2][16][72];
    __shared__ _Float16 zero16[8];

    const int tid  = threadIdx.x;
    const int w    = tid >> 6;
    const int grp  = w >> 2;
    const int cg   = w & 3;
    const int lane = tid & 63;
    const int quad = lane >> 4;
    const int l15  = lane & 15;
    const int hc   = cg * 16 + l15;
    const int n0   = blockIdx.x * 16;

    for (int i = tid; i < 16 * SXW / 2; i += 512) ((unsigned*)sxp)[i] = 0u;
    for (int i = tid; i < 2 * 16 * 72 / 2; i += 512) ((unsigned*)h0buf)[i] = 0u;
    for (int i = tid; i < 2 * 16 * 72 / 2; i += 512) ((unsigned*)h1buf)[i] = 0u;
    if (tid < 4) ((unsigned*)zero16)[tid] = 0u;
    __syncthreads();

    for (int idx = tid; idx < 16 * TT * DF; idx += 512) {
        const int m = idx / (TT * DF);
        const int r = idx - m * (TT * DF);
        const int t = r / DF;
        const int d = r - t * DF;
        sxp[m][t * 8 + d] = (_Float16)x[(size_t)(n0 + m) * (TT * DF) + r];
    }

    half8 wA[4][2], wB[4][2];
    float bias[4];
    half8 hzero;
    #pragma unroll
    for (int j = 0; j < 8; j++) hzero[j] = (_Float16)0.f;

    if (grp == 0) {
        #pragma unroll
        for (int nt = 0; nt < 4; nt++) {
            const int g = nt * 64 + hc;
            wA[nt][0] = ldw8(Whh0 + (size_t)g * HH + quad * 8);
            wA[nt][1] = ldw8(Whh0 + (size_t)g * HH + 32 + quad * 8);
            bias[nt]  = bih0[g] + bhh0[g];
            half8 t = hzero;
            if (quad == 0) {
                #pragma unroll
                for (int j = 0; j < DF; j++) t[j] = (_Float16)Wih0[g * DF + j];
            }
            wB[nt][0] = t;
            wB[nt][1] = hzero;
        }
    } else {
        #pragma unroll
        for (int nt = 0; nt < 4; nt++) {
            const int g = nt * 64 + hc;
            wA[nt][0] = ldw8(Wih1 + (size_t)g * HH + quad * 8);
            wA[nt][1] = ldw8(Wih1 + (size_t)g * HH + 32 + quad * 8);
            wB[nt][0] = ldw8(Whh1 + (size_t)g * HH + quad * 8);
            wB[nt][1] = ldw8(Whh1 + (size_t)g * HH + 32 + quad * 8);
            bias[nt]  = bih1[g] + bhh1[g];
        }
    }

    float cs[4] = {0.f, 0.f, 0.f, 0.f};
    __syncthreads();

    for (int i = 0; i <= TT; i++) {
        const int p = i & 1;
        if (grp == 0) {
            if (i < TT) {
                const half8 a0 = *(const half8*)&h0buf[p][l15][quad * 8];
                const half8 a1 = *(const half8*)&h0buf[p][l15][32 + quad * 8];
                const _Float16* xap = (quad == 0) ? &sxp[l15][i * 8] : zero16;
                const half8 ax = *(const half8*)xap;
                f32x4 gv[4];
                #pragma unroll
                for (int nt = 0; nt < 4; nt++) {
                    f32x4 c; c[0] = bias[nt]; c[1] = bias[nt]; c[2] = bias[nt]; c[3] = bias[nt];
                    c = MFMA16(ax, wB[nt][0], c);
                    c = MFMA16(a0, wA[nt][0], c);
                    c = MFMA16(a1, wA[nt][1], c);
                    gv[nt] = c;
                }
                _Float16 (*h0w)[72] = h0buf[p ^ 1];
                #pragma unroll
                for (int reg = 0; reg < 4; reg++) {
                    const float gi = gv[0][reg], gf = gv[1][reg], gc = gv[2][reg], go = gv[3][reg];
                    const float cc = sigmoidf_(gf) * cs[reg] + sigmoidf_(gi) * tanhf_(gc);
                    cs[reg] = cc;
                    h0w[quad * 4 + reg][hc] = (_Float16)(sigmoidf_(go) * tanhf_(cc));
                }
            }
        } else {
            if (i > 0) {
                const half8 a00 = *(const half8*)&h0buf[p][l15][quad * 8];
                const half8 a01 = *(const half8*)&h0buf[p][l15][32 + quad * 8];
                const half8 a10 = *(const half8*)&h1buf[p][l15][quad * 8];
                const half8 a11 = *(const half8*)&h1buf[p][l15][32 + quad * 8];
                f32x4 gv[4];
                #pragma unroll
                for (int nt = 0; nt < 4; nt++) {
                    f32x4 c; c[0] = bias[nt]; c[1] = bias[nt]; c[2] = bias[nt]; c[3] = bias[nt];
                    c = MFMA16(a00, wA[nt][0], c);
                    c = MFMA16(a01, wA[nt][1], c);
                    c = MFMA16(a10, wB[nt][0], c);
                    c = MFMA16(a11, wB[nt][1], c);
                    gv[nt] = c;
                }
                _Float16 (*h1w)[72] = h1buf[p ^ 1];
                #pragma unroll
                for (int reg = 0; reg < 4; reg++) {
                    const float gi = gv[0][reg], gf = gv[1][reg], gc = gv[2][reg], go = gv[3][reg];
                    const float cc = sigmoidf_(gf) * cs[reg] + sigmoidf_(gi) * tanhf_(gc);
                    cs[reg] = cc;
                    const float hv = sigmoidf_(go) * tanhf_(cc);
                    h1w[quad * 4 + reg][hc] = (_Float16)hv;
                    if (i == TT) last_out[(size_t)(n0 + quad * 4 + reg) * HH + hc] = hv;
                }
            }
        }
        __syncthreads();
    }
}

// ---------------------------------------------------------------------------
// Barrier-state init.
// ---------------------------------------------------------------------------
__global__ void bar_init_kernel(int* bar) {
    if (threadIdx.x == 0) { bar[0] = 0; bar[1] = 0; }
}

// Device-scope grid barrier. Arrival: one atomic RMW per block. Poll: atomic
// LOAD (relaxed, agent scope) — coherent but non-serializing, unlike the RMW
// poll that caused R8's ~40µs/barrier line contention.
__device__ __forceinline__ void gridbar(int* __restrict__ bar) {
    __syncthreads();
    if (threadIdx.x == 0) {
        int* cnt = bar;
        int* gen = bar + 1;
        __threadfence();
        const int g = __hip_atomic_load(gen, __ATOMIC_RELAXED, __HIP_MEMORY_SCOPE_AGENT);
        if (__hip_atomic_fetch_add(cnt, 1, __ATOMIC_ACQ_REL, __HIP_MEMORY_SCOPE_AGENT) == NB - 1) {
            __hip_atomic_store(cnt, 0, __ATOMIC_RELAXED, __HIP_MEMORY_SCOPE_AGENT);
            __hip_atomic_fetch_add(gen, 1, __ATOMIC_RELEASE, __HIP_MEMORY_SCOPE_AGENT);
        } else {
            while (__hip_atomic_load(gen, __ATOMIC_RELAXED, __HIP_MEMORY_SCOPE_AGENT) == g)
                __builtin_amdgcn_s_sleep(2);
        }
        __threadfence();
    }
    __syncthreads();
}

// ---------------------------------------------------------------------------
// GAT+FC tail, persistent, 4 grid barriers. Block b owns nodes [32b, 32b+32).
// Rank ordering uses raw s1 (== ordering by d = s1 - s1max; monotone shift),
// letting rank/scatter merge into the phase after barrier 1.
// ---------------------------------------------------------------------------
__global__ __launch_bounds__(256, 1)
void gat_tail_kernel(const float* __restrict__ last,
                     const float* __restrict__ Wt, const float* __restrict__ bt,
                     const float* __restrict__ a,
                     const float* __restrict__ Wfc, const float* __restrict__ bfc,
                     const float* __restrict__ Wout, const float* __restrict__ bout,
                     float* __restrict__ blkmax, float* __restrict__ s1g,
                     float* __restrict__ sortedRow, float* __restrict__ sortedD,
                     float* __restrict__ chunkSum, float* __restrict__ PP,
                     int* __restrict__ bar,
                     float* __restrict__ out)
{
    __shared__ float big[NN];          // 32 KB: s1 stage (P1), sortedD stage (P4)
    __shared__ float sWfc[HH][HH + 1]; // 16.25 KB, transposed Wfc
    __shared__ float sv1[HH], sv2[HH], sbF[HH], saF[HH];
    __shared__ float sc12[2];
    __shared__ float sS1[32], sS2[32], sZ[32], sAi[32], sBi[32], sU[32], sWw[32];
    __shared__ int   sRank[32];
    __shared__ float sred[256];

    const int tid  = threadIdx.x;
    const int b    = blockIdx.x;
    const int j0   = b * 32;
    const int wv   = tid >> 6;
    const int lane = tid & 63;

    // ===== P0: small-vector precompute; s1/s2 for slice; block max ==========
    for (int idx = tid; idx < HH * HH; idx += 256) {
        const int h = idx >> 6, d = idx & 63;
        sWfc[d][h] = Wfc[idx];
    }
    if (tid < HH) {
        float a1 = 0.f, a2 = 0.f;
        #pragma unroll 8
        for (int h = 0; h < HH; h++) {
            const float wt = Wt[h * HH + tid];
            a1 += wt * a[h];
            a2 += wt * a[HH + h];
        }
        sv1[tid] = a1; sv2[tid] = a2;
    } else if (tid == 64 || tid == 65) {
        const float* av = a + (tid - 64) * HH;
        float c = 0.f;
        #pragma unroll 8
        for (int h = 0; h < HH; h++) c += bt[h] * av[h];
        sc12[tid - 64] = c;
    } else if (tid >= 128 && tid < 192) {
        sbF[tid - 128] = bfc[tid - 128];
    } else if (tid >= 192) {
        saF[tid - 192] = Wout[tid - 192];
    }
    __syncthreads();

    #pragma unroll
    for (int jj = 0; jj < 8; jj++) {
        const int jl = wv * 8 + jj;
        const float lv = last[(size_t)(j0 + jl) * HH + lane];
        float p1 = lv * sv1[lane];
        float p2 = lv * sv2[lane];
        #pragma unroll
        for (int off = 32; off > 0; off >>= 1) {
            p1 += __shfl_xor(p1, off);
            p2 += __shfl_xor(p2, off);
        }
        if (lane == 0) {
            const float s1v = p1 + sc12[0];
            sS1[jl] = s1v; sS2[jl] = p2 + sc12[1];
            s1g[j0 + jl] = s1v;
        }
    }
    __syncthreads();
    if (tid < 32) {
        float m = sS1[tid];
        #pragma unroll
        for (int off = 16; off > 0; off >>= 1) m = fmaxf(m, __shfl_xor(m, off));
        if (tid == 0) blkmax[b] = m;
    }
    gridbar(bar);

    // ===== P1: s1max; factors; rank (by raw s1); scatter ====================
    sred[tid] = blkmax[tid];
    __syncthreads();
    for (int s = 128; s > 0; s >>= 1) {
        if (tid < s) sred[tid] = fmaxf(sred[tid], sred[tid + s]);
        __syncthreads();
    }
    const float s1max = sred[0];
    if (tid < 32) {
        const float z  = sS2[tid] + s1max;
        const float mi = lrelu_(z);
        sZ[tid]  = z;
        sAi[tid] = __expf(z - mi);
        sBi[tid] = __expf(0.01f * z - mi);
        const float d = sS1[tid] - s1max;
        sU[tid]  = __expf(d);
        sWw[tid] = __expf(0.01f * d);
        sRank[tid] = 0;
    }
    for (int idx = tid; idx < NN; idx += 256) big[idx] = s1g[idx];
    __syncthreads();
    {
        const int jl = tid & 31;
        const int part = tid >> 5;            // 0..7
        const float sj = sS1[jl];
        const int jglob = j0 + jl;
        int cnt = 0;
        const int k0 = part * (NN / 8);
        #pragma unroll 4
        for (int k = k0; k < k0 + NN / 8; k++) {
            const float sk = big[k];
            cnt += (sk < sj || (sk == sj && k < jglob)) ? 1 : 0;
        }
        atomicAdd(&sRank[jl], cnt);
    }
    __syncthreads();
    #pragma unroll
    for (int jj = 0; jj < 8; jj++) {
        const int jl = wv * 8 + jj;
        const int r = sRank[jl];
        const float u = sU[jl], w = sWw[jl];
        const float lv = last[(size_t)(j0 + jl) * HH + lane];
        float* row = sortedRow + (size_t)r * RS;
        row[lane]      = u * lv;
        row[64 + lane] = w * lv;
        if (lane == 0) {
            row[128] = u;
            row[129] = w;
            sortedD[r] = sS1[jl] - s1max;
        }
    }
    gridbar(bar);

    // ===== P2: chunk column sums ============================================
    if (tid < 130) {
        const float* base = sortedRow + (size_t)b * CH * RS + tid;
        float s = 0.f;
        #pragma unroll 8
        for (int r = 0; r < CH; r++) s += base[(size_t)r * RS];
        chunkSum[b * RS + tid] = s;
    }
    gridbar(bar);

    // ===== P3: fill PP (prefix for W-group, suffix for U-group) =============
    if (tid < 130) {
        const int c = tid;
        const bool rev = (c < 64) || (c == 128);
        float run = 0.f;
        #pragma unroll 8
        for (int bb = 0; bb < NB; bb++) {
            const float v = chunkSum[bb * RS + c];
            run += ((rev ? (bb > b) : (bb < b)) ? v : 0.f);
        }
        if (rev) {
            if (b == NB - 1) PP[(size_t)NN * RS + c] = 0.f;
            #pragma unroll 4
            for (int r = CH - 1; r >= 0; r--) {
                const size_t t = (size_t)b * CH + r;
                run += sortedRow[t * RS + c];
                PP[t * RS + c] = run;
            }
        } else {
            #pragma unroll 4
            for (int r = 0; r < CH; r++) {
                const size_t t = (size_t)b * CH + r;
                PP[t * RS + c] = run;
                run += sortedRow[t * RS + c];
            }
            if (b == NB - 1) PP[(size_t)NN * RS + c] = run;
        }
    }
    gridbar(bar);

    // ===== P4: apply + FC head ==============================================
    for (int idx = tid; idx < NN; idx += 256) big[idx] = sortedD[idx];
    __syncthreads();
    const float bo = bout[0];
    #pragma unroll
    for (int jj = 0; jj < 8; jj++) {
        const int il = wv * 8 + jj;
        const int i  = j0 + il;
        const float zi = sZ[il];
        int lo = 0, hi = NN;
        for (int iter = 0; iter < 13; iter++) {
            if (lo < hi) {
                const int mid = (lo + hi) >> 1;
                const float dm = big[mid];
                if (zi + dm > 0.f) hi = mid; else lo = mid + 1;
            }
        }
        const float* rowp = PP + (size_t)lo * RS;
        const float pu  = rowp[lane];
        const float pw  = rowp[64 + lane];
        const float pud = rowp[128];
        const float pwd = rowp[129];
        const float ai = sAi[il], bi = sBi[il];
        const float numer = bi * pw + ai * pu;
        const float den   = bi * pwd + ai * pud;
        const float lv = last[(size_t)i * HH + lane];
        const float gv = numer * __builtin_amdgcn_rcpf(den) + lv;
        float acc = sbF[lane];
        #pragma unroll
        for (int d = 0; d < HH; d++) acc += __shfl(gv, d) * sWfc[d][lane];
        float prod = lrelu_(acc) * saF[lane];
        #pragma unroll
        for (int off = 32; off > 0; off >>= 1) prod += __shfl_xor(prod, off);
        if (lane == 0) out[i] = prod + bo;
    }
}

extern "C" void kernel_launch(void* const* d_in, const int* in_sizes, int n_in,
                              void* d_out, int out_size, void* d_ws, size_t ws_size,
                              hipStream_t stream)
{
    (void)in_sizes; (void)n_in; (void)out_size; (void)ws_size;
    const float* x    = (const float*)d_in[0];
    const float* Wih0 = (const float*)d_in[1];
    const float* Whh0 = (const float*)d_in[2];
    const float* bih0 = (const float*)d_in[3];
    const float* bhh0 = (const float*)d_in[4];
    const float* Wih1 = (const float*)d_in[5];
    const float* Whh1 = (const float*)d_in[6];
    const float* bih1 = (const float*)d_in[7];
    const float* bhh1 = (const float*)d_in[8];
    const float* Wt   = (const float*)d_in[9];
    const float* bt   = (const float*)d_in[10];
    const float* a    = (const float*)d_in[11];
    const float* Wfc  = (const float*)d_in[12];
    const float* bfc  = (const float*)d_in[13];
    const float* Wout = (const float*)d_in[14];
    const float* bout = (const float*)d_in[15];
    float* out = (float*)d_out;

    float* ws        = (float*)d_ws;
    float* last      = ws;                          // N*H
    float* s1g       = last + (size_t)NN*HH;        // N
    float* blkmax    = s1g + NN;                    // 256
    float* sortedD   = blkmax + 256;                // N
    float* sortedRow = sortedD + NN;                // N*RS
    float* PP        = sortedRow + (size_t)NN*RS;   // (N+1)*RS
    float* chunkSum  = PP + (size_t)(NN+1)*RS;      // NB*RS
    int*   bar       = (int*)(chunkSum + NB*RS);    // 2 ints

    lstm_fused_kernel<<<dim3(NN / 16), dim3(512), 0, stream>>>(
        x, Wih0, Whh0, bih0, bhh0, Wih1, Whh1, bih1, bhh1, last);
    bar_init_kernel<<<dim3(1), dim3(64), 0, stream>>>(bar);
    gat_tail_kernel<<<dim3(NB), dim3(256), 0, stream>>>(
        last, Wt, bt, a, Wfc, bfc, Wout, bout,
        blkmax, s1g, sortedRow, sortedD, chunkSum, PP, bar, out);
}

// Round 11
// 259.859 us; speedup vs baseline: 1.6065x; 1.6065x over previous
//
#include <hip/hip_runtime.h>

#define NN 8192
#define TT 60
#define DF 6
#define HH 64
#define GG 256   // 4*H
#define RS 132   // payload width: [0..63] u*last, [64..127] w*last, [128] u, [129] w
#define CH 32    // ranks per chunk/block
#define NB 256   // chunks

typedef _Float16 half8 __attribute__((ext_vector_type(8)));
typedef float f32x4 __attribute__((ext_vector_type(4)));
#define MFMA16(a, b, c) __builtin_amdgcn_mfma_f32_16x16x32_f16((a), (b), (c), 0, 0, 0)

__device__ __forceinline__ float sigmoidf_(float x) {
    return __builtin_amdgcn_rcpf(1.0f + __expf(-x));
}
__device__ __forceinline__ float tanhf_(float x) {
    return __builtin_fmaf(2.0f, __builtin_amdgcn_rcpf(1.0f + __expf(-2.0f * x)), -1.0f);
}
__device__ __forceinline__ float lrelu_(float x) { return x > 0.0f ? x : 0.01f * x; }

__device__ __forceinline__ half8 ldw8(const float* __restrict__ p) {
    const float4* q = (const float4*)p;
    float4 u = q[0], v = q[1];
    half8 r;
    r[0]=(_Float16)u.x; r[1]=(_Float16)u.y; r[2]=(_Float16)u.z; r[3]=(_Float16)u.w;
    r[4]=(_Float16)v.x; r[5]=(_Float16)v.y; r[6]=(_Float16)v.z; r[7]=(_Float16)v.w;
    return r;
}

// ---------------------------------------------------------------------------
// K1: MFMA 2-layer LSTM (R7 pipelined structure) + fused GAT-prep epilogue:
// s1 = h1·(Wt^T a1) + bt·a1, s2 likewise (hgat never materialized).
// ---------------------------------------------------------------------------
#define SXW (TT * 8 + 8)

__global__ __launch_bounds__(512, 4)
void lstm_fused_kernel(const float* __restrict__ x,
                       const float* __restrict__ Wih0, const float* __restrict__ Whh0,
                       const float* __restrict__ bih0, const float* __restrict__ bhh0,
                       const float* __restrict__ Wih1, const float* __restrict__ Whh1,
                       const float* __restrict__ bih1, const float* __restrict__ bhh1,
                       const float* __restrict__ Wt, const float* __restrict__ bt,
                       const float* __restrict__ av,
                       float* __restrict__ last_out,
                       float* __restrict__ s1g, float* __restrict__ s2g)
{
    __shared__ _Float16 sxp[16][SXW];
    __shared__ _Float16 h0buf[2][16][72];
    __shared__ _Float16 h1buf[2][16][72];
    __shared__ _Float16 zero16[8];
    __shared__ float sv1[HH], sv2[HH], sc12[2];

    const int tid  = threadIdx.x;
    const int w    = tid >> 6;
    const int grp  = w >> 2;
    const int cg   = w & 3;
    const int lane = tid & 63;
    const int quad = lane >> 4;
    const int l15  = lane & 15;
    const int hc   = cg * 16 + l15;
    const int n0   = blockIdx.x * 16;

    for (int i = tid; i < 16 * SXW / 2; i += 512) ((unsigned*)sxp)[i] = 0u;
    for (int i = tid; i < 2 * 16 * 72 / 2; i += 512) ((unsigned*)h0buf)[i] = 0u;
    for (int i = tid; i < 2 * 16 * 72 / 2; i += 512) ((unsigned*)h1buf)[i] = 0u;
    if (tid < 4) ((unsigned*)zero16)[tid] = 0u;
    __syncthreads();

    for (int idx = tid; idx < 16 * TT * DF; idx += 512) {
        const int m = idx / (TT * DF);
        const int r = idx - m * (TT * DF);
        const int t = r / DF;
        const int d = r - t * DF;
        sxp[m][t * 8 + d] = (_Float16)x[(size_t)(n0 + m) * (TT * DF) + r];
    }

    // GAT-prep small vectors (redundant per block, overlaps with weight loads)
    if (tid < HH) {
        float a1 = 0.f, a2 = 0.f;
        #pragma unroll 8
        for (int h = 0; h < HH; h++) {
            const float wt = Wt[h * HH + tid];
            a1 += wt * av[h];
            a2 += wt * av[HH + h];
        }
        sv1[tid] = a1; sv2[tid] = a2;
    } else if (tid == 64 || tid == 65) {
        const float* ap = av + (tid - 64) * HH;
        float c = 0.f;
        #pragma unroll 8
        for (int h = 0; h < HH; h++) c += bt[h] * ap[h];
        sc12[tid - 64] = c;
    }

    half8 wA[4][2], wB[4][2];
    float bias[4];
    half8 hzero;
    #pragma unroll
    for (int j = 0; j < 8; j++) hzero[j] = (_Float16)0.f;

    if (grp == 0) {
        #pragma unroll
        for (int nt = 0; nt < 4; nt++) {
            const int g = nt * 64 + hc;
            wA[nt][0] = ldw8(Whh0 + (size_t)g * HH + quad * 8);
            wA[nt][1] = ldw8(Whh0 + (size_t)g * HH + 32 + quad * 8);
            bias[nt]  = bih0[g] + bhh0[g];
            half8 t = hzero;
            if (quad == 0) {
                #pragma unroll
                for (int j = 0; j < DF; j++) t[j] = (_Float16)Wih0[g * DF + j];
            }
            wB[nt][0] = t;
            wB[nt][1] = hzero;
        }
    } else {
        #pragma unroll
        for (int nt = 0; nt < 4; nt++) {
            const int g = nt * 64 + hc;
            wA[nt][0] = ldw8(Wih1 + (size_t)g * HH + quad * 8);
            wA[nt][1] = ldw8(Wih1 + (size_t)g * HH + 32 + quad * 8);
            wB[nt][0] = ldw8(Whh1 + (size_t)g * HH + quad * 8);
            wB[nt][1] = ldw8(Whh1 + (size_t)g * HH + 32 + quad * 8);
            bias[nt]  = bih1[g] + bhh1[g];
        }
    }

    float cs[4] = {0.f, 0.f, 0.f, 0.f};
    __syncthreads();

    for (int i = 0; i <= TT; i++) {
        const int p = i & 1;
        if (grp == 0) {
            if (i < TT) {
                const half8 a0 = *(const half8*)&h0buf[p][l15][quad * 8];
                const half8 a1 = *(const half8*)&h0buf[p][l15][32 + quad * 8];
                const _Float16* xap = (quad == 0) ? &sxp[l15][i * 8] : zero16;
                const half8 ax = *(const half8*)xap;
                f32x4 gv[4];
                #pragma unroll
                for (int nt = 0; nt < 4; nt++) {
                    f32x4 c; c[0] = bias[nt]; c[1] = bias[nt]; c[2] = bias[nt]; c[3] = bias[nt];
                    c = MFMA16(ax, wB[nt][0], c);
                    c = MFMA16(a0, wA[nt][0], c);
                    c = MFMA16(a1, wA[nt][1], c);
                    gv[nt] = c;
                }
                _Float16 (*h0w)[72] = h0buf[p ^ 1];
                #pragma unroll
                for (int reg = 0; reg < 4; reg++) {
                    const float gi = gv[0][reg], gf = gv[1][reg], gc = gv[2][reg], go = gv[3][reg];
                    const float cc = sigmoidf_(gf) * cs[reg] + sigmoidf_(gi) * tanhf_(gc);
                    cs[reg] = cc;
                    h0w[quad * 4 + reg][hc] = (_Float16)(sigmoidf_(go) * tanhf_(cc));
                }
            }
        } else {
            if (i > 0) {
                const half8 a00 = *(const half8*)&h0buf[p][l15][quad * 8];
                const half8 a01 = *(const half8*)&h0buf[p][l15][32 + quad * 8];
                const half8 a10 = *(const half8*)&h1buf[p][l15][quad * 8];
                const half8 a11 = *(const half8*)&h1buf[p][l15][32 + quad * 8];
                f32x4 gv[4];
                #pragma unroll
                for (int nt = 0; nt < 4; nt++) {
                    f32x4 c; c[0] = bias[nt]; c[1] = bias[nt]; c[2] = bias[nt]; c[3] = bias[nt];
                    c = MFMA16(a00, wA[nt][0], c);
                    c = MFMA16(a01, wA[nt][1], c);
                    c = MFMA16(a10, wB[nt][0], c);
                    c = MFMA16(a11, wB[nt][1], c);
                    gv[nt] = c;
                }
                _Float16 (*h1w)[72] = h1buf[p ^ 1];
                #pragma unroll
                for (int reg = 0; reg < 4; reg++) {
                    const float gi = gv[0][reg], gf = gv[1][reg], gc = gv[2][reg], go = gv[3][reg];
                    const float cc = sigmoidf_(gf) * cs[reg] + sigmoidf_(gi) * tanhf_(gc);
                    cs[reg] = cc;
                    const float hv = sigmoidf_(go) * tanhf_(cc);
                    h1w[quad * 4 + reg][hc] = (_Float16)hv;
                    if (i == TT) last_out[(size_t)(n0 + quad * 4 + reg) * HH + hc] = hv;
                }
            }
        }
        __syncthreads();
    }

    // ---- epilogue: s1/s2 from final h1 (in h1buf[1]; TT=60 even) ----
    {
        const _Float16 (*hf)[72] = h1buf[1];
        const int r  = tid >> 5;
        const int c0 = tid & 31;
        const float h1a = (float)hf[r][c0];
        const float h1b = (float)hf[r][c0 + 32];
        float p1 = h1a * sv1[c0] + h1b * sv1[c0 + 32];
        float p2 = h1a * sv2[c0] + h1b * sv2[c0 + 32];
        #pragma unroll
        for (int off = 16; off > 0; off >>= 1) {
            p1 += __shfl_xor(p1, off);
            p2 += __shfl_xor(p2, off);
        }
        if (c0 == 0) {
            s1g[n0 + r] = p1 + sc12[0];
            s2g[n0 + r] = p2 + sc12[1];
        }
    }
}

// ---------------------------------------------------------------------------
// K2: rank + factors. Block b owns nodes [32b,32b+32). Stages all s1 in LDS;
// computes s1max redundantly (deterministic: identical data+order per block);
// rank by raw s1 (monotone == rank by d); writes iperm (rank->node) & sortedD.
// ---------------------------------------------------------------------------
__global__ __launch_bounds__(256)
void rankfac_kernel(const float* __restrict__ s1g, const float* __restrict__ s2g,
                    float* __restrict__ Z, float* __restrict__ Ai, float* __restrict__ Bi,
                    float* __restrict__ U, float* __restrict__ W,
                    int* __restrict__ iperm, float* __restrict__ sortedD)
{
    __shared__ float sb[NN];      // 32 KB
    __shared__ float sred[256];
    __shared__ int   sRank[32];
    const int tid = threadIdx.x;
    const int b   = blockIdx.x;
    const int j0  = b * 32;

    for (int idx = tid; idx < NN; idx += 256) sb[idx] = s1g[idx];
    if (tid < 32) sRank[tid] = 0;
    __syncthreads();

    float m = -1e30f;
    for (int idx = tid; idx < NN; idx += 256) m = fmaxf(m, sb[idx]);
    sred[tid] = m;
    __syncthreads();
    for (int s = 128; s > 0; s >>= 1) {
        if (tid < s) sred[tid] = fmaxf(sred[tid], sred[tid + s]);
        __syncthreads();
    }
    const float s1max = sred[0];

    if (tid < 32) {
        const int j = j0 + tid;
        const float z  = s2g[j] + s1max;
        const float mi = lrelu_(z);
        Z[j]  = z;
        Ai[j] = __expf(z - mi);
        Bi[j] = __expf(0.01f * z - mi);
        const float d = sb[j] - s1max;
        U[j] = __expf(d);
        W[j] = __expf(0.01f * d);
    }
    {
        const int jl = tid & 31;
        const int part = tid >> 5;          // 0..7
        const float sj = sb[j0 + jl];
        const int jg = j0 + jl;
        int cnt = 0;
        const int k0 = part * (NN / 8);
        #pragma unroll 4
        for (int k = k0; k < k0 + NN / 8; k++) {
            const float sk = sb[k];
            cnt += (sk < sj || (sk == sj && k < jg)) ? 1 : 0;
        }
        atomicAdd(&sRank[jl], cnt);
    }
    __syncthreads();
    if (tid < 32) {
        const int r = sRank[tid];
        iperm[r] = j0 + tid;
        sortedD[r] = sb[j0 + tid] - s1max;
    }
}

// ---------------------------------------------------------------------------
// K3: chunk column sums via iperm gather (coalesced row loads into LDS).
// ---------------------------------------------------------------------------
__global__ __launch_bounds__(256)
void scanA_kernel(const float* __restrict__ last, const float* __restrict__ U,
                  const float* __restrict__ W, const int* __restrict__ iperm,
                  float* __restrict__ chunkSum)
{
    __shared__ int   sj[CH];
    __shared__ float su[CH], sw[CH];
    __shared__ float al[CH][HH], bl[CH][HH];
    const int tid = threadIdx.x;
    const int b   = blockIdx.x;
    if (tid < CH) {
        const int j = iperm[b * CH + tid];
        sj[tid] = j; su[tid] = U[j]; sw[tid] = W[j];
    }
    __syncthreads();
    for (int idx = tid; idx < CH * HH; idx += 256) {
        const int rr = idx >> 6, c = idx & 63;
        const float lv = last[(size_t)sj[rr] * HH + c];
        al[rr][c] = su[rr] * lv;
        bl[rr][c] = sw[rr] * lv;
    }
    __syncthreads();
    if (tid < 130) {
        const int c = tid;
        float s = 0.f;
        if (c < 64) {
            for (int rr = 0; rr < CH; rr++) s += al[rr][c];
        } else if (c < 128) {
            for (int rr = 0; rr < CH; rr++) s += bl[rr][c - 64];
        } else if (c == 128) {
            for (int rr = 0; rr < CH; rr++) s += su[rr];
        } else {
            for (int rr = 0; rr < CH; rr++) s += sw[rr];
        }
        chunkSum[b * RS + c] = s;
    }
}

// ---------------------------------------------------------------------------
// K4: per-column exclusive scan over the 256 chunk sums (one block per column;
// U-group scans in reversed order = direct suffix, no cancellation).
// ---------------------------------------------------------------------------
__global__ __launch_bounds__(256)
void scanB_kernel(const float* __restrict__ chunkSum, float* __restrict__ chunkOfs)
{
    __shared__ float wt[4];
    const int c   = blockIdx.x;               // 0..129
    const bool rev = (c < 64) || (c == 128);
    const int tid = threadIdx.x;
    const int lane = tid & 63, wv = tid >> 6;
    const int idx = rev ? (NB - 1 - tid) : tid;
    const float orig = chunkSum[idx * RS + c];
    float v = orig;
    #pragma unroll
    for (int d = 1; d < 64; d <<= 1) {
        const float t = __shfl_up(v, d);
        if (lane >= d) v += t;
    }
    if (lane == 63) wt[wv] = v;
    __syncthreads();
    float off = 0.f;
    for (int q = 0; q < wv; q++) off += wt[q];
    chunkOfs[idx * RS + c] = v + off - orig;   // exclusive in scan order
}

// ---------------------------------------------------------------------------
// K5: fill PP rows for this block's 32 ranks (gathered payload in LDS).
// ---------------------------------------------------------------------------
__global__ __launch_bounds__(256)
void scanC_kernel(const float* __restrict__ last, const float* __restrict__ U,
                  const float* __restrict__ W, const int* __restrict__ iperm,
                  const float* __restrict__ chunkOfs, float* __restrict__ PP)
{
    __shared__ int   sj[CH];
    __shared__ float su[CH], sw[CH];
    __shared__ float al[CH][HH], bl[CH][HH];
    const int tid = threadIdx.x;
    const int b   = blockIdx.x;
    if (tid < CH) {
        const int j = iperm[b * CH + tid];
        sj[tid] = j; su[tid] = U[j]; sw[tid] = W[j];
    }
    __syncthreads();
    for (int idx = tid; idx < CH * HH; idx += 256) {
        const int rr = idx >> 6, c = idx & 63;
        const float lv = last[(size_t)sj[rr] * HH + c];
        al[rr][c] = su[rr] * lv;
        bl[rr][c] = sw[rr] * lv;
    }
    __syncthreads();
    if (tid < 130) {
        const int c = tid;
        const bool rev = (c < 64) || (c == 128);
        float run = chunkOfs[b * RS + c];
        if (rev) {
            if (b == NB - 1) PP[(size_t)NN * RS + c] = 0.f;
            for (int rr = CH - 1; rr >= 0; rr--) {
                const float val = (c < 64) ? al[rr][c] : su[rr];
                run += val;
                PP[(size_t)(b * CH + rr) * RS + c] = run;
            }
        } else {
            for (int rr = 0; rr < CH; rr++) {
                PP[(size_t)(b * CH + rr) * RS + c] = run;
                run += (c < 128) ? bl[rr][c - 64] : sw[rr];
            }
            if (b == NB - 1) PP[(size_t)NN * RS + c] = run;
        }
    }
}

// ---------------------------------------------------------------------------
// K6: apply + FC head. Interleaved binary searches (LDS sortedD), then batched
// independent PP/last gathers, then FC.
// ---------------------------------------------------------------------------
__global__ __launch_bounds__(256)
void applyfc_kernel(const float* __restrict__ last,
                    const float* __restrict__ Z, const float* __restrict__ Ai, const float* __restrict__ Bi,
                    const float* __restrict__ sortedD, const float* __restrict__ PP,
                    const float* __restrict__ Wfc, const float* __restrict__ bfc,
                    const float* __restrict__ Wout, const float* __restrict__ bout,
                    float* __restrict__ out)
{
    __shared__ float sdD[NN];          // 32 KB
    __shared__ float sW[HH][HH + 1];
    __shared__ float sbF[HH], saF[HH];
    const int tid = threadIdx.x;
    for (int idx = tid; idx < NN; idx += 256) sdD[idx] = sortedD[idx];
    for (int idx = tid; idx < HH * HH; idx += 256) {
        const int h = idx >> 6, d = idx & 63;
        sW[d][h] = Wfc[idx];
    }
    if (tid < HH) { sbF[tid] = bfc[tid]; saF[tid] = Wout[tid]; }
    __syncthreads();

    const int wv = tid >> 6, lane = tid & 63;
    const int i0 = blockIdx.x * 32 + wv * 8;
    float zi[8]; int lo[8], hi[8];
    #pragma unroll
    for (int q = 0; q < 8; q++) { zi[q] = Z[i0 + q]; lo[q] = 0; hi[q] = NN; }
    for (int iter = 0; iter < 13; iter++) {
        #pragma unroll
        for (int q = 0; q < 8; q++) {
            if (lo[q] < hi[q]) {
                const int mid = (lo[q] + hi[q]) >> 1;
                const float dm = sdD[mid];
                if (zi[q] + dm > 0.f) hi[q] = mid; else lo[q] = mid + 1;
            }
        }
    }
    float gv[8];
    #pragma unroll
    for (int q = 0; q < 8; q++) {
        const int i = i0 + q;
        const float* rowp = PP + (size_t)lo[q] * RS;
        const float pu  = rowp[lane];
        const float pw  = rowp[64 + lane];
        const float pud = rowp[128];
        const float pwd = rowp[129];
        const float ai = Ai[i], bi = Bi[i];
        const float numer = bi * pw + ai * pu;
        const float den   = bi * pwd + ai * pud;
        const float lv = last[(size_t)i * HH + lane];
        gv[q] = numer * __builtin_amdgcn_rcpf(den) + lv;
    }
    const float bo = bout[0];
    #pragma unroll
    for (int q = 0; q < 8; q++) {
        float acc = sbF[lane];
        #pragma unroll
        for (int d = 0; d < HH; d++) acc += __shfl(gv[q], d) * sW[d][lane];
        float prod = lrelu_(acc) * saF[lane];
        #pragma unroll
        for (int off = 32; off > 0; off >>= 1) prod += __shfl_xor(prod, off);
        if (lane == 0) out[i0 + q] = prod + bo;
    }
}

extern "C" void kernel_launch(void* const* d_in, const int* in_sizes, int n_in,
                              void* d_out, int out_size, void* d_ws, size_t ws_size,
                              hipStream_t stream)
{
    (void)in_sizes; (void)n_in; (void)out_size; (void)ws_size;
    const float* x    = (const float*)d_in[0];
    const float* Wih0 = (const float*)d_in[1];
    const float* Whh0 = (const float*)d_in[2];
    const float* bih0 = (const float*)d_in[3];
    const float* bhh0 = (const float*)d_in[4];
    const float* Wih1 = (const float*)d_in[5];
    const float* Whh1 = (const float*)d_in[6];
    const float* bih1 = (const float*)d_in[7];
    const float* bhh1 = (const float*)d_in[8];
    const float* Wt   = (const float*)d_in[9];
    const float* bt   = (const float*)d_in[10];
    const float* a    = (const float*)d_in[11];
    const float* Wfc  = (const float*)d_in[12];
    const float* bfc  = (const float*)d_in[13];
    const float* Wout = (const float*)d_in[14];
    const float* bout = (const float*)d_in[15];
    float* out = (float*)d_out;

    float* ws       = (float*)d_ws;
    float* last     = ws;                           // N*H
    float* s1g      = last + (size_t)NN*HH;         // N
    float* s2g      = s1g + NN;                     // N
    float* Z        = s2g + NN;                     // N
    float* Ai       = Z + NN;                       // N
    float* Bi       = Ai + NN;                      // N
    float* U        = Bi + NN;                      // N
    float* W        = U + NN;                       // N
    float* sortedD  = W + NN;                       // N
    int*   iperm    = (int*)(sortedD + NN);         // N ints
    float* chunkSum = (float*)(iperm + NN);         // NB*RS
    float* chunkOfs = chunkSum + NB*RS;             // NB*RS
    float* PP       = chunkOfs + NB*RS;             // (N+1)*RS

    lstm_fused_kernel<<<dim3(NN / 16), dim3(512), 0, stream>>>(
        x, Wih0, Whh0, bih0, bhh0, Wih1, Whh1, bih1, bhh1,
        Wt, bt, a, last, s1g, s2g);
    rankfac_kernel<<<dim3(NB), dim3(256), 0, stream>>>(
        s1g, s2g, Z, Ai, Bi, U, W, iperm, sortedD);
    scanA_kernel<<<dim3(NB), dim3(256), 0, stream>>>(last, U, W, iperm, chunkSum);
    scanB_kernel<<<dim3(130), dim3(256), 0, stream>>>(chunkSum, chunkOfs);
    scanC_kernel<<<dim3(NB), dim3(256), 0, stream>>>(last, U, W, iperm, chunkOfs, PP);
    applyfc_kernel<<<dim3(NB), dim3(256), 0, stream>>>(
        last, Z, Ai, Bi, sortedD, PP, Wfc, bfc, Wout, bout, out);
}